// Round 2
// baseline (310.407 us; speedup 1.0000x reference)
//
#include <hip/hip_runtime.h>
#include <hip/hip_cooperative_groups.h>

// GCN N=100k, E=1.6M, H=64 — algebraic collapse + fixed-capacity bucket binning.
//
// Math (layer-1 input is [N,1], so each node's hidden state is a scalar function):
//   s[d] = dinv[d]*(sum_{src->d} dinv[src]*x[src] + dinv[d]*x[d])
//   relu(s*w1+b1) @ w2 = s*P^{sign(s)} + B^{sign(s)}   (P±,B± precomputed 64-vecs)
//   layer-2 scalars: a±[d], c±[d] (sign-split sums of dinv_s*s_s and dinv_s)
//   out[d] = relu(dinv[d]*(a+P+ + a-P- + c+B+ + c-B-) + b2) . wfc + bfc
//
// R2: single cooperative mega-kernel. Phases separated by grid.sync():
//   phase0 (chunk bx): bin edges into fixed bucket regions (LDS stash, run-
//           reservation cursor atomics, overflow->ovbuf)   [identical to R0 k_place]
//   phase1 (buckets 2bx,2bx+1): stage packed region into LDS sedge ONCE,
//           LDS histogram -> dinv (register-only!), y = dinv*x
//   phase2: acc[localdst] += y[src] from LDS sedge -> val2
//   phase3: sign-split accumulate of val2[src] from LDS sedge + fused epilogue
// dinv array eliminated (per-node dinv persists in a register across syncs).
// R1's global deg atomics REVERTED (62MB write-through + atomic serialization).
//
// Dispatches: k_init -> k_mega (cooperative). 2 total.

#define HCH 64
#define CHUNK 4096
#define BSH 7
#define BSZ 128          // nodes per bucket
#define NBMAX 1024
#define CAPMAX 2688      // max packed entries per bucket stageable in LDS

namespace cg = cooperative_groups;

__device__ __forceinline__ void lds_addf(float* p, float v) {
    __hip_atomic_fetch_add(p, v, __ATOMIC_RELAXED, __HIP_MEMORY_SCOPE_WORKGROUP);
}

// one block: init cursors + ov counter; P[0..255]=P+,P-,B+,B-; P[256]=B-nonzero flag
__global__ __launch_bounds__(512) void k_init(int nb, int cap,
                                              int* __restrict__ cursor,
                                              int* __restrict__ ov_cursor,
                                              const float* __restrict__ w1,
                                              const float* __restrict__ b1,
                                              const float* __restrict__ w2,
                                              float* __restrict__ P) {
    __shared__ float part[8][4][HCH];
    __shared__ float fsum;
    int t = threadIdx.x;
    for (int i = t; i < nb; i += 512) cursor[i] = i * cap;
    if (t == 0) { *ov_cursor = 0; fsum = 0.f; }
    int j = t & 63, seg = t >> 6;
    float pp = 0.f, pm = 0.f, bp = 0.f, bm = 0.f;
#pragma unroll
    for (int kk = 0; kk < 8; kk++) {
        int k = seg * 8 + kk;
        float w = w1[k], b = b1[k], v = w2[k * HCH + j];
        if (w > 0.f) { pp += w * v; bp += b * v; }
        else if (w < 0.f) { pm += w * v; bm += b * v; }
        else { float rb = b > 0.f ? b : 0.f; bp += rb * v; bm += rb * v; }
    }
    part[seg][0][j] = pp; part[seg][1][j] = pm;
    part[seg][2][j] = bp; part[seg][3][j] = bm;
    __syncthreads();
    if (t < 4 * HCH) {
        int c = t >> 6, jj = t & 63;
        float s = 0.f;
#pragma unroll
        for (int g = 0; g < 8; g++) s += part[g][c][jj];
        P[t] = s;
        if (c >= 2) lds_addf(&fsum, fabsf(s));
    }
    __syncthreads();
    if (t == 0) P[4 * HCH] = fsum;
}

union SMem {
    struct {  // phase 0 (place)
        int h[NBMAX];
        int basel[NBMAX];
        int avail[NBMAX];
        int lpv[CHUNK];
        short lb[CHUNK];
    } pl;                              // 36864 B
    struct {  // phases 1-3 (aggregate, 2 buckets per block)
        int sedge[2][CAPMAX];          // 21504 B — staged packed regions
        int cnt[2][BSZ];               // 1024 B
        float acc[2][BSZ];             // 1024 B
        float aa[2][2 * BSZ];          // 2048 B
        float cc[2][2 * BSZ];          // 2048 B
        float sP[4 * HCH];             // 1024 B
        float sb2[HCH];                // 256 B
        float swfc[HCH];               // 256 B
        float sflag;
    } ag;                              // 29188 B
};

__global__ __launch_bounds__(512, 4) void k_mega(
    const int* __restrict__ src, const int* __restrict__ dst, int e,
    int nb, int cap,
    int* __restrict__ cursor, int* __restrict__ ov_cursor,
    int* __restrict__ packed, int2* __restrict__ ovbuf,
    const float* __restrict__ x, int n,
    const float* __restrict__ P, const float* __restrict__ b2,
    const float* __restrict__ wfc, const float* __restrict__ bfc,
    float* __restrict__ y, float2* __restrict__ val2,
    float* __restrict__ out) {
    cg::grid_group grid = cg::this_grid();
    __shared__ SMem sm;
    int t = threadIdx.x;
    int bx = blockIdx.x;

    // ---------------- phase 0: place (chunk = bx) ----------------
    int nchunk = (e + CHUNK - 1) / CHUNK;
    if (bx < nchunk) {
        for (int i = t; i < nb; i += 512) sm.pl.h[i] = 0;
        __syncthreads();
        int cbase = bx * CHUNK;
        int rem = min(e - cbase, CHUNK);
#pragma unroll
        for (int g = 0; g < 2; g++) {
            int li = t * 8 + g * 4;
            if (li + 3 < rem) {
                int4 s4 = *(const int4*)(src + cbase + li);
                int4 d4 = *(const int4*)(dst + cbase + li);
#pragma unroll
                for (int q = 0; q < 4; q++) {
                    int sv = (q == 0) ? s4.x : (q == 1) ? s4.y : (q == 2) ? s4.z : s4.w;
                    int dv = (q == 0) ? d4.x : (q == 1) ? d4.y : (q == 2) ? d4.z : d4.w;
                    int b = dv >> BSH;
                    atomicAdd(&sm.pl.h[b], 1);
                    sm.pl.lpv[li + q] = sv | ((dv & (BSZ - 1)) << 17);
                    sm.pl.lb[li + q] = (short)b;
                }
            } else {
                for (int q = li; q < rem && q < li + 4; q++) {
                    int sv = src[cbase + q], dv = dst[cbase + q];
                    int b = dv >> BSH;
                    atomicAdd(&sm.pl.h[b], 1);
                    sm.pl.lpv[q] = sv | ((dv & (BSZ - 1)) << 17);
                    sm.pl.lb[q] = (short)b;
                }
            }
        }
        __syncthreads();
        for (int i = t; i < nb; i += 512) {
            int my = sm.pl.h[i];
            int av = 0, base = 0;
            if (my) {
                base = atomicAdd(&cursor[i], my);
                int room = (i + 1) * cap - base;
                av = room < 0 ? 0 : (room > my ? my : room);
            }
            sm.pl.basel[i] = base;
            sm.pl.avail[i] = av;
            sm.pl.h[i] = 0;  // reuse as local run cursor
        }
        __syncthreads();
        for (int li = t * 8; li < t * 8 + 8 && li < rem; li++) {
            int b = sm.pl.lb[li];
            int pv = sm.pl.lpv[li];
            int loc = atomicAdd(&sm.pl.h[b], 1);
            if (loc < sm.pl.avail[b]) {
                packed[sm.pl.basel[b] + loc] = pv;
            } else {
                int op = atomicAdd(ov_cursor, 1);
                ovbuf[op] = make_int2(pv & 0x1FFFF, (b << BSH) | (pv >> 17));
            }
        }
    }
    grid.sync();

    // ---------------- phase 1: stage + degree + y ----------------
    int b0 = bx * 2;
    bool has = b0 < nb;
    if (t < 4 * HCH) sm.ag.sP[t] = P[t];
    if (t >= 256 && t < 320) sm.ag.sb2[t - 256] = b2[t - 256];
    if (t >= 320 && t < 384) sm.ag.swfc[t - 320] = wfc[t - 320];
    if (t == 448) sm.ag.sflag = P[4 * HCH];
    if (has && t < 256) ((int*)sm.ag.cnt)[t] = 0;
    __syncthreads();

    int bc[2] = {0, 0};
    int ovc = 0;
    if (has) {
        bc[0] = min(cursor[b0] - b0 * cap, cap);
        if (b0 + 1 < nb) bc[1] = min(cursor[b0 + 1] - (b0 + 1) * cap, cap);
        ovc = *ov_cursor;
#pragma unroll
        for (int u = 0; u < 2; u++) {
            int bbase = (b0 + u) * cap;
            for (int i0 = t * 4; i0 < bc[u]; i0 += 2048) {
                if (i0 + 3 < bc[u]) {
                    int4 p = *(const int4*)(packed + bbase + i0);
                    *(int4*)(&sm.ag.sedge[u][i0]) = p;
                    atomicAdd(&sm.ag.cnt[u][p.x >> 17], 1);
                    atomicAdd(&sm.ag.cnt[u][p.y >> 17], 1);
                    atomicAdd(&sm.ag.cnt[u][p.z >> 17], 1);
                    atomicAdd(&sm.ag.cnt[u][p.w >> 17], 1);
                } else {
                    for (int i = i0; i < bc[u] && i < i0 + 4; i++) {
                        int p = packed[bbase + i];
                        sm.ag.sedge[u][i] = p;
                        atomicAdd(&sm.ag.cnt[u][p >> 17], 1);
                    }
                }
            }
        }
        for (int i = t; i < ovc; i += 512) {
            int2 o = ovbuf[i];
            int ob = o.y >> BSH;
            if (ob == b0) atomicAdd(&sm.ag.cnt[0][o.y & (BSZ - 1)], 1);
            else if (ob == b0 + 1) atomicAdd(&sm.ag.cnt[1][o.y & (BSZ - 1)], 1);
        }
    }
    __syncthreads();

    int ub = t >> 7, tt = t & (BSZ - 1);
    int mynode = -1;
    float mydv = 0.f, myx = 0.f;
    if (has && t < 256) {
        int bb = b0 + ub;
        int node = (bb << BSH) + tt;
        if (bb < nb && node < n) {
            mynode = node;
            mydv = rsqrtf((float)(sm.ag.cnt[ub][tt] + 1));  // +1 self-loop
            myx = x[node];
            y[node] = mydv * myx;
        }
    }
    grid.sync();

    // ---------------- phase 2: layer-1 aggregate ----------------
    if (has && t < 256) ((float*)sm.ag.acc)[t] = 0.f;
    __syncthreads();
    if (has) {
#pragma unroll
        for (int u = 0; u < 2; u++) {
            for (int i0 = t * 4; i0 < bc[u]; i0 += 2048) {
                if (i0 + 3 < bc[u]) {
                    int4 p = *(const int4*)(&sm.ag.sedge[u][i0]);
                    float y0 = y[p.x & 0x1FFFF], y1 = y[p.y & 0x1FFFF];
                    float y2 = y[p.z & 0x1FFFF], y3 = y[p.w & 0x1FFFF];
                    lds_addf(&sm.ag.acc[u][p.x >> 17], y0);
                    lds_addf(&sm.ag.acc[u][p.y >> 17], y1);
                    lds_addf(&sm.ag.acc[u][p.z >> 17], y2);
                    lds_addf(&sm.ag.acc[u][p.w >> 17], y3);
                } else {
                    for (int i = i0; i < bc[u] && i < i0 + 4; i++) {
                        int p = sm.ag.sedge[u][i];
                        lds_addf(&sm.ag.acc[u][p >> 17], y[p & 0x1FFFF]);
                    }
                }
            }
        }
        for (int i = t; i < ovc; i += 512) {
            int2 o = ovbuf[i];
            int ob = o.y >> BSH;
            if (ob == b0) lds_addf(&sm.ag.acc[0][o.y & (BSZ - 1)], y[o.x]);
            else if (ob == b0 + 1) lds_addf(&sm.ag.acc[1][o.y & (BSZ - 1)], y[o.x]);
        }
    }
    __syncthreads();
    float2 myv2 = make_float2(0.f, 0.f);
    if (mynode >= 0) {
        float s = mydv * (sm.ag.acc[ub][tt] + mydv * myx);
        myv2 = make_float2(mydv * s, mydv);
        val2[mynode] = myv2;
    }
    grid.sync();

    // ---------------- phase 3: layer-2 sign-split + epilogue ----------------
    if (has) {
        ((float*)sm.ag.aa)[t] = 0.f;
        ((float*)sm.ag.cc)[t] = 0.f;
    }
    __syncthreads();
    bool useB = sm.ag.sflag != 0.f;
    if (has) {
#pragma unroll
        for (int u = 0; u < 2; u++) {
            for (int i0 = t * 4; i0 < bc[u]; i0 += 2048) {
                if (i0 + 3 < bc[u]) {
                    int4 p = *(const int4*)(&sm.ag.sedge[u][i0]);
                    float2 v0 = val2[p.x & 0x1FFFF], v1 = val2[p.y & 0x1FFFF];
                    float2 v2 = val2[p.z & 0x1FFFF], v3 = val2[p.w & 0x1FFFF];
                    int o0 = (v0.x > 0.f ? 0 : BSZ) + (p.x >> 17);
                    int o1 = (v1.x > 0.f ? 0 : BSZ) + (p.y >> 17);
                    int o2 = (v2.x > 0.f ? 0 : BSZ) + (p.z >> 17);
                    int o3 = (v3.x > 0.f ? 0 : BSZ) + (p.w >> 17);
                    lds_addf(&sm.ag.aa[u][o0], v0.x); lds_addf(&sm.ag.aa[u][o1], v1.x);
                    lds_addf(&sm.ag.aa[u][o2], v2.x); lds_addf(&sm.ag.aa[u][o3], v3.x);
                    if (useB) {
                        lds_addf(&sm.ag.cc[u][o0], v0.y); lds_addf(&sm.ag.cc[u][o1], v1.y);
                        lds_addf(&sm.ag.cc[u][o2], v2.y); lds_addf(&sm.ag.cc[u][o3], v3.y);
                    }
                } else {
                    for (int i = i0; i < bc[u] && i < i0 + 4; i++) {
                        int p = sm.ag.sedge[u][i];
                        float2 v = val2[p & 0x1FFFF];
                        int off = (v.x > 0.f ? 0 : BSZ) + (p >> 17);
                        lds_addf(&sm.ag.aa[u][off], v.x);
                        if (useB) lds_addf(&sm.ag.cc[u][off], v.y);
                    }
                }
            }
        }
        for (int i = t; i < ovc; i += 512) {
            int2 o = ovbuf[i];
            int ob = o.y >> BSH;
            if (ob == b0 || ob == b0 + 1) {
                int u = ob - b0;
                float2 v = val2[o.x];
                int off = (v.x > 0.f ? 0 : BSZ) + (o.y & (BSZ - 1));
                lds_addf(&sm.ag.aa[u][off], v.x);
                if (useB) lds_addf(&sm.ag.cc[u][off], v.y);
            }
        }
    }
    __syncthreads();
    if (mynode >= 0) {
        float a_p = sm.ag.aa[ub][tt], a_m = sm.ag.aa[ub][BSZ + tt];
        float c_p = sm.ag.cc[ub][tt], c_m = sm.ag.cc[ub][BSZ + tt];
        if (myv2.x > 0.f) { a_p += myv2.x; c_p += myv2.y; }
        else              { a_m += myv2.x; c_m += myv2.y; }
        float acc = 0.f;
#pragma unroll 8
        for (int j = 0; j < HCH; j++) {
            float z = mydv * (a_p * sm.ag.sP[j] + a_m * sm.ag.sP[HCH + j] +
                              c_p * sm.ag.sP[2 * HCH + j] + c_m * sm.ag.sP[3 * HCH + j]) +
                      sm.ag.sb2[j];
            z = z > 0.f ? z : 0.f;
            acc += z * sm.ag.swfc[j];
        }
        out[mynode] = acc + bfc[0];
    }
}

extern "C" void kernel_launch(void* const* d_in, const int* in_sizes, int n_in,
                              void* d_out, int out_size, void* d_ws, size_t ws_size,
                              hipStream_t stream) {
    const float* x   = (const float*)d_in[0];
    const int*   ei  = (const int*)d_in[1];
    const float* w1  = (const float*)d_in[2];
    const float* b1  = (const float*)d_in[3];
    const float* w2  = (const float*)d_in[4];
    const float* b2  = (const float*)d_in[5];
    const float* wfc = (const float*)d_in[6];
    const float* bfc = (const float*)d_in[7];
    float* out = (float*)d_out;

    const int n = in_sizes[0];      // 100000
    const int e = in_sizes[1] / 2;  // 1600000
    const int* src = ei;
    const int* dst = ei + e;

    const int nb = (n + BSZ - 1) >> BSH;          // 782 buckets
    int avg = (e + nb - 1) / nb;                  // ~2047
    int cap = ((avg + avg / 4 + 64) + 15) & ~15;  // ~13 sigma headroom, 16-aligned
    if (cap > CAPMAX) cap = CAPMAX;               // excess spills to ovbuf (correct)

    auto al = [](size_t v) { return (v + 255) & ~(size_t)255; };
    char* ws = (char*)d_ws;
    size_t o = 0;
    int* cursor    = (int*)(ws + o);  o = al(o + (size_t)NBMAX * 4);
    int* ov_cursor = (int*)(ws + o);  o = al(o + 256);
    float* y     = (float*)(ws + o);  o = al(o + (size_t)n * 4);
    float2* val2 = (float2*)(ws + o); o = al(o + (size_t)n * 8);
    float* P     = (float*)(ws + o);  o = al(o + (4 * HCH + 8) * 4);
    int* packed  = (int*)(ws + o);    o = al(o + (size_t)nb * cap * 4);
    int2* ovbuf  = (int2*)(ws + o);   o = al(o + (size_t)e * 8);
    (void)ws_size;

    const int nchunk = (e + CHUNK - 1) / CHUNK;  // 391 chunks
    const int nbk2 = (nb + 1) / 2;               // 391 bucket-pairs
    int grid = nchunk > nbk2 ? nchunk : nbk2;    // 391

    k_init<<<1, 512, 0, stream>>>(nb, cap, cursor, ov_cursor, w1, b1, w2, P);

    void* args[] = {(void*)&src, (void*)&dst, (void*)&e, (void*)&nb, (void*)&cap,
                    (void*)&cursor, (void*)&ov_cursor, (void*)&packed, (void*)&ovbuf,
                    (void*)&x, (void*)&n, (void*)&P, (void*)&b2, (void*)&wfc,
                    (void*)&bfc, (void*)&y, (void*)&val2, (void*)&out};
    hipLaunchCooperativeKernel((void*)k_mega, dim3(grid), dim3(512), args, 0, stream);
}

// Round 3
// 129.461 us; speedup vs baseline: 2.3977x; 2.3977x over previous
//
#include <hip/hip_runtime.h>

// GCN N=100k, E=1.6M, H=64 — algebraic collapse + fixed-capacity bucket binning.
//
// Math (layer-1 input is [N,1], so each node's hidden state is a scalar function):
//   s[d] = dinv[d]*(sum_{src->d} dinv[src]*x[src] + dinv[d]*x[d])
//   relu(s*w1+b1) @ w2 = s*P^{sign(s)} + B^{sign(s)}   (P±,B± precomputed 64-vecs)
//   layer-2 scalars: a±[d], c±[d] (sign-split sums of dinv_s*s_s and dinv_s)
//   out[d] = relu(dinv[d]*(a+P+ + a-P- + c+B+ + c-B-) + b2) . wfc + bfc
//
// R3 (back to R0's 5-kernel structure; R2's grid.sync megakernel reverted —
// 35% occupancy + XCD L2 flush per sync = 2.3x regression):
//   k_place: CHUNK 4096->8192 (halves cursor-atomic chain depth per bucket word,
//   196 blocks) + bucket-SORTED LDS stash via block scan, so the global write-out
//   is a linear sweep (consecutive lanes -> consecutive addresses in ~10-edge
//   runs) instead of a 64-distinct-line random scatter per wave.
//   k_bagg1: self term uses y[node] (= dinv*x), drops the x re-read.
//
// Dispatches: k_init -> k_place -> k_bdeg -> k_bagg1 -> k_bagg2 (5 total).

#define HCH 64
#define CHUNK 8192
#define BSH 7
#define BSZ 128          // nodes per bucket
#define NBMAX 1024

__device__ __forceinline__ void lds_addf(float* p, float v) {
    __hip_atomic_fetch_add(p, v, __ATOMIC_RELAXED, __HIP_MEMORY_SCOPE_WORKGROUP);
}

// one block: init cursors + ov counter; P[0..255]=P+,P-,B+,B-; P[256]=B-nonzero flag
__global__ __launch_bounds__(512) void k_init(int nb, int cap,
                                              int* __restrict__ cursor,
                                              int* __restrict__ ov_cursor,
                                              const float* __restrict__ w1,
                                              const float* __restrict__ b1,
                                              const float* __restrict__ w2,
                                              float* __restrict__ P) {
    __shared__ float part[8][4][HCH];
    __shared__ float fsum;
    int t = threadIdx.x;
    for (int i = t; i < nb; i += 512) cursor[i] = i * cap;
    if (t == 0) { *ov_cursor = 0; fsum = 0.f; }
    int j = t & 63, seg = t >> 6;
    float pp = 0.f, pm = 0.f, bp = 0.f, bm = 0.f;
#pragma unroll
    for (int kk = 0; kk < 8; kk++) {
        int k = seg * 8 + kk;
        float w = w1[k], b = b1[k], v = w2[k * HCH + j];
        if (w > 0.f) { pp += w * v; bp += b * v; }
        else if (w < 0.f) { pm += w * v; bm += b * v; }
        else { float rb = b > 0.f ? b : 0.f; bp += rb * v; bm += rb * v; }
    }
    part[seg][0][j] = pp; part[seg][1][j] = pm;
    part[seg][2][j] = bp; part[seg][3][j] = bm;
    __syncthreads();
    if (t < 4 * HCH) {
        int c = t >> 6, jj = t & 63;
        float s = 0.f;
#pragma unroll
        for (int g = 0; g < 8; g++) s += part[g][c][jj];
        P[t] = s;
        if (c >= 2) lds_addf(&fsum, fabsf(s));
    }
    __syncthreads();
    if (t == 0) P[4 * HCH] = fsum;
}

// bin edges into fixed bucket regions, bucket-sorted within the chunk so the
// global write-out is a coalesced linear sweep.
__global__ __launch_bounds__(512) void k_place(const int* __restrict__ src,
                                               const int* __restrict__ dst, int e,
                                               int nb, int cap,
                                               int* __restrict__ cursor,
                                               int* __restrict__ ov_cursor,
                                               int* __restrict__ packed,
                                               int2* __restrict__ ovbuf) {
    __shared__ int h[NBMAX];       // counts -> placement cursor
    __shared__ int scanE[NBMAX];   // chunk-local exclusive prefix
    __shared__ int basel[NBMAX];
    __shared__ int avail[NBMAX];
    __shared__ int slpv[CHUNK];    // bucket-sorted packed values
    __shared__ short ssb[CHUNK];   // bucket id per sorted slot
    __shared__ int wsum[8];
    int t = threadIdx.x;
    for (int i = t; i < NBMAX; i += 512) h[i] = 0;
    __syncthreads();
    int cbase = blockIdx.x * CHUNK;
    int rem = min(e - cbase, CHUNK);

    // ---- pass 1: histogram (dst only) ----
#pragma unroll
    for (int k = 0; k < CHUNK / 2048; k++) {
        int li = (k * 512 + t) * 4;
        if (li + 3 < rem) {
            int4 d4 = *(const int4*)(dst + cbase + li);
            atomicAdd(&h[d4.x >> BSH], 1);
            atomicAdd(&h[d4.y >> BSH], 1);
            atomicAdd(&h[d4.z >> BSH], 1);
            atomicAdd(&h[d4.w >> BSH], 1);
        } else {
            for (int q = li; q < rem && q < li + 4; q++)
                atomicAdd(&h[dst[cbase + q] >> BSH], 1);
        }
    }
    __syncthreads();

    // ---- reservation (overlaps the scan) + block scan over NBMAX entries ----
    int v0 = h[2 * t], v1 = h[2 * t + 1];
    for (int i = t; i < nb; i += 512) {
        int my = h[i];
        int av = 0, base = 0;
        if (my) {
            base = atomicAdd(&cursor[i], my);
            int room = (i + 1) * cap - base;
            av = room < 0 ? 0 : (room > my ? my : room);
        }
        basel[i] = base;
        avail[i] = av;
    }
    int lane = t & 63, wid = t >> 6;
    int s = v0 + v1;
    int incl = s;
#pragma unroll
    for (int d = 1; d < 64; d <<= 1) {
        int o = __shfl_up(incl, d, 64);
        if (lane >= d) incl += o;
    }
    if (lane == 63) wsum[wid] = incl;
    __syncthreads();                 // all h reads done; wsum level-1 written
    if (t < 8) {
        int v = wsum[t];
        int inc2 = v;
#pragma unroll
        for (int d = 1; d < 8; d <<= 1) {
            int o = __shfl_up(inc2, d, 8);
            if (t >= d) inc2 += o;
        }
        wsum[t] = inc2 - v;          // exclusive wave offset
    }
    for (int i = t; i < NBMAX; i += 512) h[i] = 0;  // reuse as placement cursor
    __syncthreads();
    int excl = incl - s + wsum[wid];
    scanE[2 * t] = excl;
    scanE[2 * t + 1] = excl + v0;
    __syncthreads();

    // ---- pass 2: re-read edges (L2-hot), place bucket-sorted into LDS ----
#pragma unroll
    for (int k = 0; k < CHUNK / 2048; k++) {
        int li = (k * 512 + t) * 4;
        if (li + 3 < rem) {
            int4 s4 = *(const int4*)(src + cbase + li);
            int4 d4 = *(const int4*)(dst + cbase + li);
#pragma unroll
            for (int q = 0; q < 4; q++) {
                int sv = (q == 0) ? s4.x : (q == 1) ? s4.y : (q == 2) ? s4.z : s4.w;
                int dv = (q == 0) ? d4.x : (q == 1) ? d4.y : (q == 2) ? d4.z : d4.w;
                int b = dv >> BSH;
                int pos = scanE[b] + atomicAdd(&h[b], 1);
                slpv[pos] = sv | ((dv & (BSZ - 1)) << 17);
                ssb[pos] = (short)b;
            }
        } else {
            for (int q = li; q < rem && q < li + 4; q++) {
                int sv = src[cbase + q], dv = dst[cbase + q];
                int b = dv >> BSH;
                int pos = scanE[b] + atomicAdd(&h[b], 1);
                slpv[pos] = sv | ((dv & (BSZ - 1)) << 17);
                ssb[pos] = (short)b;
            }
        }
    }
    __syncthreads();

    // ---- pass 3: linear write-out (consecutive lanes -> consecutive addrs) ----
    for (int jj = t; jj < rem; jj += 512) {
        int b = ssb[jj];
        int loc = jj - scanE[b];
        int pv = slpv[jj];
        if (loc < avail[b]) {
            packed[basel[b] + loc] = pv;
        } else {
            int op = atomicAdd(ov_cursor, 1);
            ovbuf[op] = make_int2(pv & 0x1FFFF, (b << BSH) | (pv >> 17));
        }
    }
}

// per bucket: int histogram of local dst -> deg -> dinv, y = dinv*x
__global__ __launch_bounds__(512) void k_bdeg(const int* __restrict__ packed,
                                              const int* __restrict__ cursor,
                                              const int* __restrict__ ov_cursor,
                                              const int2* __restrict__ ovbuf,
                                              int cap, const float* __restrict__ x, int n,
                                              float* __restrict__ dinv,
                                              float* __restrict__ y) {
    __shared__ int cnt[BSZ];
    int bk = blockIdx.x, t = threadIdx.x;
    int bbase = bk * cap;
    int bcnt = min(cursor[bk] - bbase, cap);
    if (t < BSZ) cnt[t] = 0;
    __syncthreads();
    for (int base = 0; base < bcnt; base += 2048) {
        int i0 = base + t * 4;
        if (i0 + 3 < bcnt) {
            int4 p = *(const int4*)(packed + bbase + i0);
            atomicAdd(&cnt[p.x >> 17], 1);
            atomicAdd(&cnt[p.y >> 17], 1);
            atomicAdd(&cnt[p.z >> 17], 1);
            atomicAdd(&cnt[p.w >> 17], 1);
        } else {
            for (int i = i0; i < bcnt && i < i0 + 4; i++)
                atomicAdd(&cnt[packed[bbase + i] >> 17], 1);
        }
    }
    int ovc = *ov_cursor;
    for (int i = t; i < ovc; i += 512) {
        int2 o = ovbuf[i];
        if ((o.y >> BSH) == bk) atomicAdd(&cnt[o.y & (BSZ - 1)], 1);
    }
    __syncthreads();
    int node = (bk << BSH) + t;
    if (t < BSZ && node < n) {
        float dv = rsqrtf((float)(cnt[t] + 1));  // +1 self-loop
        dinv[node] = dv;
        y[node] = dv * x[node];
    }
}

// per bucket: acc[localdst] += y[src] -> s -> val2=(dinv*s, dinv)
__global__ __launch_bounds__(512) void k_bagg1(const int* __restrict__ packed,
                                               const int* __restrict__ cursor,
                                               const int* __restrict__ ov_cursor,
                                               const int2* __restrict__ ovbuf,
                                               int cap,
                                               const float* __restrict__ dinv,
                                               const float* __restrict__ y, int n,
                                               float2* __restrict__ val2) {
    __shared__ float acc[BSZ];
    int bk = blockIdx.x, t = threadIdx.x;
    int bbase = bk * cap;
    int bcnt = min(cursor[bk] - bbase, cap);
    if (t < BSZ) acc[t] = 0.f;
    __syncthreads();
    for (int base = 0; base < bcnt; base += 2048) {
        int i0 = base + t * 4;
        if (i0 + 3 < bcnt) {
            int4 p = *(const int4*)(packed + bbase + i0);
            float y0 = y[p.x & 0x1FFFF], y1 = y[p.y & 0x1FFFF];
            float y2 = y[p.z & 0x1FFFF], y3 = y[p.w & 0x1FFFF];
            lds_addf(&acc[p.x >> 17], y0);
            lds_addf(&acc[p.y >> 17], y1);
            lds_addf(&acc[p.z >> 17], y2);
            lds_addf(&acc[p.w >> 17], y3);
        } else {
            for (int i = i0; i < bcnt && i < i0 + 4; i++) {
                int p = packed[bbase + i];
                lds_addf(&acc[p >> 17], y[p & 0x1FFFF]);
            }
        }
    }
    int ovc = *ov_cursor;
    for (int i = t; i < ovc; i += 512) {
        int2 o = ovbuf[i];
        if ((o.y >> BSH) == bk) lds_addf(&acc[o.y & (BSZ - 1)], y[o.x]);
    }
    __syncthreads();
    int node = (bk << BSH) + t;
    if (t < BSZ && node < n) {
        float dv = dinv[node];
        float s = dv * (acc[t] + y[node]);  // y[node] = dv*x[node]
        val2[node] = make_float2(dv * s, dv);
    }
}

// per bucket: sign-split accumulate of val2[src] + fused epilogue -> out
__global__ __launch_bounds__(512) void k_bagg2(const int* __restrict__ packed,
                                               const int* __restrict__ cursor,
                                               const int* __restrict__ ov_cursor,
                                               const int2* __restrict__ ovbuf,
                                               int cap, const float2* __restrict__ val2,
                                               const float* __restrict__ dinv,
                                               const float* __restrict__ P,
                                               const float* __restrict__ b2,
                                               const float* __restrict__ wfc,
                                               const float* __restrict__ bfc,
                                               float* __restrict__ out, int n) {
    __shared__ float aa[2 * BSZ];   // [0..BSZ): positive, [BSZ..2BSZ): negative
    __shared__ float cc[2 * BSZ];
    __shared__ float sP[4 * HCH], sb2[HCH], swfc[HCH];
    __shared__ float sflag;
    int bk = blockIdx.x, t = threadIdx.x;
    int bbase = bk * cap;
    int bcnt = min(cursor[bk] - bbase, cap);
    if (t < 2 * BSZ) { aa[t] = 0.f; cc[t] = 0.f; }
    if (t < 4 * HCH) sP[t] = P[t];
    if (t >= 256 && t < 320) sb2[t - 256] = b2[t - 256];
    if (t >= 320 && t < 384) swfc[t - 320] = wfc[t - 320];
    if (t == 448) sflag = P[4 * HCH];
    __syncthreads();
    bool useB = sflag != 0.f;
    for (int base = 0; base < bcnt; base += 2048) {
        int i0 = base + t * 4;
        if (i0 + 3 < bcnt) {
            int4 p = *(const int4*)(packed + bbase + i0);
            float2 v0 = val2[p.x & 0x1FFFF], v1 = val2[p.y & 0x1FFFF];
            float2 v2 = val2[p.z & 0x1FFFF], v3 = val2[p.w & 0x1FFFF];
            int o0 = (v0.x > 0.f ? 0 : BSZ) + (p.x >> 17);
            int o1 = (v1.x > 0.f ? 0 : BSZ) + (p.y >> 17);
            int o2 = (v2.x > 0.f ? 0 : BSZ) + (p.z >> 17);
            int o3 = (v3.x > 0.f ? 0 : BSZ) + (p.w >> 17);
            lds_addf(&aa[o0], v0.x); lds_addf(&aa[o1], v1.x);
            lds_addf(&aa[o2], v2.x); lds_addf(&aa[o3], v3.x);
            if (useB) {
                lds_addf(&cc[o0], v0.y); lds_addf(&cc[o1], v1.y);
                lds_addf(&cc[o2], v2.y); lds_addf(&cc[o3], v3.y);
            }
        } else {
            for (int i = i0; i < bcnt && i < i0 + 4; i++) {
                int p = packed[bbase + i];
                float2 v = val2[p & 0x1FFFF];
                int off = (v.x > 0.f ? 0 : BSZ) + (p >> 17);
                lds_addf(&aa[off], v.x);
                if (useB) lds_addf(&cc[off], v.y);
            }
        }
    }
    int ovc = *ov_cursor;
    for (int i = t; i < ovc; i += 512) {
        int2 o = ovbuf[i];
        if ((o.y >> BSH) == bk) {
            float2 v = val2[o.x];
            int off = (v.x > 0.f ? 0 : BSZ) + (o.y & (BSZ - 1));
            lds_addf(&aa[off], v.x);
            if (useB) lds_addf(&cc[off], v.y);
        }
    }
    __syncthreads();
    int node = (bk << BSH) + t;
    if (t >= BSZ || node >= n) return;
    float a_p = aa[t], a_m = aa[BSZ + t], c_p = cc[t], c_m = cc[BSZ + t];
    float2 sv = val2[node];  // self-loop
    if (sv.x > 0.f) { a_p += sv.x; c_p += sv.y; }
    else            { a_m += sv.x; c_m += sv.y; }
    float dv = dinv[node];
    float acc = 0.f;
#pragma unroll 8
    for (int j = 0; j < HCH; j++) {
        float z = dv * (a_p * sP[j] + a_m * sP[HCH + j] +
                        c_p * sP[2 * HCH + j] + c_m * sP[3 * HCH + j]) + sb2[j];
        z = z > 0.f ? z : 0.f;
        acc += z * swfc[j];
    }
    out[node] = acc + bfc[0];
}

extern "C" void kernel_launch(void* const* d_in, const int* in_sizes, int n_in,
                              void* d_out, int out_size, void* d_ws, size_t ws_size,
                              hipStream_t stream) {
    const float* x   = (const float*)d_in[0];
    const int*   ei  = (const int*)d_in[1];
    const float* w1  = (const float*)d_in[2];
    const float* b1  = (const float*)d_in[3];
    const float* w2  = (const float*)d_in[4];
    const float* b2  = (const float*)d_in[5];
    const float* wfc = (const float*)d_in[6];
    const float* bfc = (const float*)d_in[7];
    float* out = (float*)d_out;

    const int n = in_sizes[0];      // 100000
    const int e = in_sizes[1] / 2;  // 1600000
    const int* src = ei;
    const int* dst = ei + e;

    const int nb = (n + BSZ - 1) >> BSH;          // 782 buckets
    int avg = (e + nb - 1) / nb;                  // ~2047
    int cap = ((avg + avg / 4 + 64) + 15) & ~15;  // ~13 sigma headroom, 16-aligned

    auto al = [](size_t v) { return (v + 255) & ~(size_t)255; };
    char* ws = (char*)d_ws;
    size_t o = 0;
    int* cursor    = (int*)(ws + o);  o = al(o + (size_t)NBMAX * 4);
    int* ov_cursor = (int*)(ws + o);  o = al(o + 256);
    float* dinv  = (float*)(ws + o);  o = al(o + (size_t)n * 4);
    float* y     = (float*)(ws + o);  o = al(o + (size_t)n * 4);
    float2* val2 = (float2*)(ws + o); o = al(o + (size_t)n * 8);
    float* P     = (float*)(ws + o);  o = al(o + (4 * HCH + 8) * 4);
    int* packed  = (int*)(ws + o);    o = al(o + (size_t)nb * cap * 4);
    int2* ovbuf  = (int2*)(ws + o);   o = al(o + (size_t)e * 8);
    (void)ws_size;

    const int nchunk = (e + CHUNK - 1) / CHUNK;  // 196 chunks

    k_init<<<1, 512, 0, stream>>>(nb, cap, cursor, ov_cursor, w1, b1, w2, P);
    k_place<<<nchunk, 512, 0, stream>>>(src, dst, e, nb, cap, cursor, ov_cursor,
                                        packed, ovbuf);
    k_bdeg<<<nb, 512, 0, stream>>>(packed, cursor, ov_cursor, ovbuf, cap, x, n, dinv, y);
    k_bagg1<<<nb, 512, 0, stream>>>(packed, cursor, ov_cursor, ovbuf, cap, dinv, y,
                                    n, val2);
    k_bagg2<<<nb, 512, 0, stream>>>(packed, cursor, ov_cursor, ovbuf, cap, val2, dinv,
                                    P, b2, wfc, bfc, out, n);
}